// Round 5
// baseline (1635.587 us; speedup 1.0000x reference)
//
#include <hip/hip_runtime.h>
#include <hip/hip_bf16.h>

#define NN 50000
#define NE 800000

__device__ __forceinline__ unsigned packbf2(float a, float b) {
  __hip_bfloat162 h = __float22bfloat162_rn(make_float2(a, b));
  return *reinterpret_cast<unsigned*>(&h);
}
__device__ __forceinline__ float bflo(unsigned u) {
  const unsigned v = u << 16;
  return __builtin_bit_cast(float, v);
}
__device__ __forceinline__ float bfhi(unsigned u) {
  const unsigned v = u & 0xffff0000u;
  return __builtin_bit_cast(float, v);
}

// ---------------- zero counts ----------------
__global__ __launch_bounds__(256) void zero_counts(int* __restrict__ counts) {
  const int i = blockIdx.x * 256 + threadIdx.x;
  if (i < NN) counts[i] = 0;
}

// ---------------- CSR build ----------------
__global__ __launch_bounds__(256) void count_kernel(const int* __restrict__ ei,
                                                    int* __restrict__ counts) {
  const int e = blockIdx.x * 256 + threadIdx.x;
  if (e < NE) atomicAdd(&counts[ei[NE + e]], 1);
}

__global__ __launch_bounds__(256) void scan_block(const int* __restrict__ counts,
                                                  int* __restrict__ ep,
                                                  int* __restrict__ blocksum) {
  const int i = blockIdx.x * 256 + threadIdx.x;
  const int lane = threadIdx.x & 63;
  const int w = threadIdx.x >> 6;
  const int v = (i < NN) ? counts[i] : 0;
  int s = v;
  #pragma unroll
  for (int off = 1; off < 64; off <<= 1) {
    const int t = __shfl_up(s, off, 64);
    if (lane >= off) s += t;
  }
  __shared__ int wsums[4];
  if (lane == 63) wsums[w] = s;
  __syncthreads();
  int add = 0;
  for (int j = 0; j < w; ++j) add += wsums[j];
  s += add;
  if (i < NN) ep[i] = s - v;  // exclusive within block
  if (threadIdx.x == 255) blocksum[blockIdx.x] = s;
}

__global__ void scan_tops(const int* __restrict__ blocksum,
                          int* __restrict__ blockoff, int n) {
  const int lane = threadIdx.x;  // 64 threads
  int carry = 0;
  for (int base = 0; base < n; base += 64) {
    const int i = base + lane;
    const int v = (i < n) ? blocksum[i] : 0;
    int s = v;
    #pragma unroll
    for (int off = 1; off < 64; off <<= 1) {
      const int t = __shfl_up(s, off, 64);
      if (lane >= off) s += t;
    }
    s += carry;
    if (i < n) blockoff[i] = s - v;  // exclusive
    carry = __shfl(s, 63, 64);
  }
}

__global__ __launch_bounds__(256) void scan_finish(const int* __restrict__ ep,
                                                   const int* __restrict__ blockoff,
                                                   int* __restrict__ cursor,
                                                   int* __restrict__ rowptr) {
  const int i = blockIdx.x * 256 + threadIdx.x;
  if (i < NN) {
    const int v = ep[i] + blockoff[blockIdx.x];
    cursor[i] = v;
    rowptr[i] = v;
  }
  if (i == 0) rowptr[NN] = NE;
}

__global__ __launch_bounds__(256) void scatter_kernel(const int* __restrict__ ei,
                                                      int* __restrict__ cursor,
                                                      int* __restrict__ ssrc,
                                                      int* __restrict__ sdst) {
  const int e = blockIdx.x * 256 + threadIdx.x;
  if (e < NE) {
    const int s = ei[e], d = ei[NE + e];
    const int p = atomicAdd(&cursor[d], 1);
    ssrc[p] = s;
    sdst[p] = d;
  }
}

// ---------------- composite weights: Wsa = W_src@Wa1, Wda = W_dst@Wa1 ----------------
// exact fp32 fold: Wa1@(a_dst - a_src) = x@Wda[dst] - x@Wsa[src] (linearity)
__global__ __launch_bounds__(256) void fold_w(const float* __restrict__ Wsrc,
                                              const float* __restrict__ Wdst,
                                              const float* __restrict__ Wa1,
                                              float* __restrict__ Wsa,
                                              float* __restrict__ Wda) {
  const int i = blockIdx.x * 256 + threadIdx.x;  // 2*128*64 = 16384 threads
  const int m = i >> 13;
  const int kj = i & 8191;
  const int k = kj >> 6, j = kj & 63;
  const float* __restrict__ W = m ? Wdst : Wsrc;
  float acc = 0.f;
  #pragma unroll 4
  for (int q = 0; q < 128; ++q) acc = fmaf(W[k * 128 + q], Wa1[q * 64 + j], acc);
  (m ? Wda : Wsa)[k * 64 + j] = acc;
}

// ---------------- node GEMMs: h = x@Wl [N,128]; as1 = x@Wsa, ad1 = x@Wda [N,64] ----------------
// wave task = (rowgroup of 16 rows) x chunk {h-lo, h-hi, as1, ad1}
__global__ __launch_bounds__(256) void gemm3_kernel(
    const float* __restrict__ x, const float* __restrict__ Wl,
    const float* __restrict__ Wsa, const float* __restrict__ Wda,
    float* __restrict__ h, float* __restrict__ as1, float* __restrict__ ad1) {
  const int wtask = __builtin_amdgcn_readfirstlane((int)((blockIdx.x * 256 + threadIdx.x) >> 6));
  if (wtask >= 3125 * 4) return;
  const int lane = threadIdx.x & 63;
  const int rg = wtask >> 2;
  const int chunk = wtask & 3;
  const float* __restrict__ W = (chunk <= 1) ? Wl : ((chunk == 2) ? Wsa : Wda);
  float* __restrict__ O = (chunk <= 1) ? h : ((chunk == 2) ? as1 : ad1);
  const int ldw = (chunk <= 1) ? 128 : 64;
  const int col = ((chunk == 1) ? 64 : 0) + lane;
  const int r0 = rg * 16;
  float acc[16];
  #pragma unroll
  for (int r = 0; r < 16; ++r) acc[r] = 0.f;
  const float4* x4 = (const float4*)x;
  #pragma unroll 1
  for (int k4 = 0; k4 < 32; ++k4) {
    const float w0 = W[(size_t)(k4 * 4 + 0) * ldw + col];  // coalesced
    const float w1 = W[(size_t)(k4 * 4 + 1) * ldw + col];
    const float w2 = W[(size_t)(k4 * 4 + 2) * ldw + col];
    const float w3 = W[(size_t)(k4 * 4 + 3) * ldw + col];
    #pragma unroll
    for (int r = 0; r < 16; ++r) {
      const float4 xr = x4[(size_t)(r0 + r) * 32 + k4];    // wave-uniform -> s_load
      acc[r] = fmaf(xr.x, w0, fmaf(xr.y, w1, fmaf(xr.z, w2, fmaf(xr.w, w3, acc[r]))));
    }
  }
  #pragma unroll
  for (int r = 0; r < 16; ++r) O[(size_t)(r0 + r) * ldw + col] = acc[r];
}

// ---------------- edge kernel: lane = one edge (CSR order, dst sorted) ----------------
// pass 1: delta (fp32) -> stash relu(delta) as packed bf16 in swizzled LDS
//         ha = (ad1[dst]-as1[src]) + relu(delta)@Wa1  (attn path fully fp32)
// pass 2: logits -> exp -> value uses stashed bf16 delta (no 8192-FMA recompute)
__global__ __launch_bounds__(128) void edge_kernel(
    const int* __restrict__ ssrc, const int* __restrict__ sdst,
    const int* __restrict__ rowptr,
    const float* __restrict__ pos,
    const float* __restrict__ hbuf,
    const float* __restrict__ as1, const float* __restrict__ ad1,
    const float* __restrict__ Wp1, const float* __restrict__ bp1,
    const float* __restrict__ Wp2, const float* __restrict__ bp2,
    const float* __restrict__ Wa1, const float* __restrict__ ba1,
    const float* __restrict__ Wa2, const float* __restrict__ ba2,
    float* __restrict__ out, float* __restrict__ stag) {
  __shared__ uint2 stash[128][32];   // 32 KB; [tid][(c4+lane)&31] -> 2-way banks (free)
  const int t = blockIdx.x * 128 + threadIdx.x;   // grid exactly covers NE
  const int lane = threadIdx.x & 63;
  const int wavebase = t & ~63;
  const int src = ssrc[t];
  const int dst = sdst[t];

  const float2 pd = ((const float2*)pos)[dst];
  const float2 ps = ((const float2*)pos)[src];
  const float p0 = pd.x - ps.x;
  const float p1 = pd.y - ps.y;

  // segmented-scan predicates over the sorted dst runs in this wave
  bool take[6];
  #pragma unroll
  for (int i = 0; i < 6; ++i) {
    const int off = 1 << i;
    const int dd = __shfl_down(dst, off, 64);
    take[i] = (lane + off < 64) && (dd == dst);
  }
  const int dup = __shfl_up(dst, 1, 64);
  const bool head = (lane == 0) || (dup != dst);

  // head classification: complete run (store final), else staging slot
  bool complete = false;
  int slot = 0;
  if (head) {
    const int r0 = rowptr[dst];
    const int r1 = rowptr[dst + 1];
    complete = (t == r0) && (r1 <= wavebase + 64);
    const bool cont = (t > r0);  // lane==0 continuation from prev wave
    slot = 2 * (wavebase >> 6) + (cont ? 0 : 1);
  }

  // pos_nn hidden: hd[k] = relu(p0*Wp1[0][k] + p1*Wp1[1][k] + bp1[k])
  float hd[64];
  #pragma unroll
  for (int k = 0; k < 64; k += 4) {
    const float4 w0 = *(const float4*)(Wp1 + k);
    const float4 w1 = *(const float4*)(Wp1 + 64 + k);
    const float4 bb = *(const float4*)(bp1 + k);
    hd[k + 0] = fmaxf(fmaf(p0, w0.x, fmaf(p1, w1.x, bb.x)), 0.f);
    hd[k + 1] = fmaxf(fmaf(p0, w0.y, fmaf(p1, w1.y, bb.y)), 0.f);
    hd[k + 2] = fmaxf(fmaf(p0, w0.z, fmaf(p1, w1.z, bb.z)), 0.f);
    hd[k + 3] = fmaxf(fmaf(p0, w0.w, fmaf(p1, w1.w, bb.w)), 0.f);
  }

  // ha init = ad1[dst] - as1[src]   (the folded Wa1@(a_dst - a_src) term)
  float ha[64];
  {
    const float4* a1d = (const float4*)(ad1 + (size_t)dst * 64);
    const float4* a1s = (const float4*)(as1 + (size_t)src * 64);
    #pragma unroll
    for (int k4 = 0; k4 < 16; ++k4) {
      const float4 a = a1d[k4];
      const float4 s = a1s[k4];
      ha[k4 * 4 + 0] = a.x - s.x;
      ha[k4 * 4 + 1] = a.y - s.y;
      ha[k4 * 4 + 2] = a.z - s.z;
      ha[k4 * 4 + 3] = a.w - s.w;
    }
  }

  // pass 1: delta_c (fp32) -> stash bf16 -> ha += relu(delta)@Wa1 (fp32)
  #pragma unroll 1
  for (int c4 = 0; c4 < 32; ++c4) {
    const float4 bb = *(const float4*)(bp2 + c4 * 4);
    float d0 = bb.x, d1 = bb.y, d2 = bb.z, d3 = bb.w;
    #pragma unroll
    for (int k = 0; k < 64; ++k) {
      const float4 w = *(const float4*)(Wp2 + k * 128 + c4 * 4);  // uniform -> s_load
      d0 = fmaf(hd[k], w.x, d0);
      d1 = fmaf(hd[k], w.y, d1);
      d2 = fmaf(hd[k], w.z, d2);
      d3 = fmaf(hd[k], w.w, d3);
    }
    const float r0 = fmaxf(d0, 0.f);
    const float r1 = fmaxf(d1, 0.f);
    const float r2 = fmaxf(d2, 0.f);
    const float r3 = fmaxf(d3, 0.f);
    uint2 q;
    q.x = packbf2(r0, r1);
    q.y = packbf2(r2, r3);
    stash[threadIdx.x][(c4 + lane) & 31] = q;
    const float u[4] = {r0, r1, r2, r3};
    #pragma unroll
    for (int j = 0; j < 4; ++j) {
      const float uj = u[j];
      const float* wa1 = Wa1 + (size_t)(c4 * 4 + j) * 64;
      #pragma unroll
      for (int k = 0; k < 64; k += 4) {
        const float4 w = *(const float4*)(wa1 + k);
        ha[k + 0] = fmaf(uj, w.x, ha[k + 0]);
        ha[k + 1] = fmaf(uj, w.y, ha[k + 1]);
        ha[k + 2] = fmaf(uj, w.z, ha[k + 2]);
        ha[k + 3] = fmaf(uj, w.w, ha[k + 3]);
      }
    }
  }

  #pragma unroll
  for (int k = 0; k < 64; k += 4) {
    const float4 bb = *(const float4*)(ba1 + k);
    ha[k + 0] = fmaxf(ha[k + 0] + bb.x, 0.f);
    ha[k + 1] = fmaxf(ha[k + 1] + bb.y, 0.f);
    ha[k + 2] = fmaxf(ha[k + 2] + bb.z, 0.f);
    ha[k + 3] = fmaxf(ha[k + 3] + bb.w, 0.f);
  }

  const float4* h4 = (const float4*)(hbuf + (size_t)src * 128);
  float* orow = out + (size_t)dst * 128;
  float* srow = stag + (size_t)slot * 256;

  // pass 2: logits -> e=exp(l) -> value = e*(h[src]+delta), segmented reduce, store
  #pragma unroll 1
  for (int c4 = 0; c4 < 32; ++c4) {
    const float4 hv = h4[c4];
    const float4 b2 = *(const float4*)(ba2 + c4 * 4);
    float l0 = b2.x, l1 = b2.y, l2 = b2.z, l3 = b2.w;
    #pragma unroll
    for (int k = 0; k < 64; ++k) {
      const float4 wa = *(const float4*)(Wa2 + k * 128 + c4 * 4);
      l0 = fmaf(ha[k], wa.x, l0);
      l1 = fmaf(ha[k], wa.y, l1);
      l2 = fmaf(ha[k], wa.z, l2);
      l3 = fmaf(ha[k], wa.w, l3);
    }
    const uint2 q = stash[threadIdx.x][(c4 + lane) & 31];
    const float del0 = bflo(q.x), del1 = bfhi(q.x);
    const float del2 = bflo(q.y), del3 = bfhi(q.y);
    float ee[4], vv[4];
    ee[0] = __expf(fmaxf(l0, 0.f)); vv[0] = ee[0] * (hv.x + del0);
    ee[1] = __expf(fmaxf(l1, 0.f)); vv[1] = ee[1] * (hv.y + del1);
    ee[2] = __expf(fmaxf(l2, 0.f)); vv[2] = ee[2] * (hv.z + del2);
    ee[3] = __expf(fmaxf(l3, 0.f)); vv[3] = ee[3] * (hv.w + del3);

    // in-wave segmented suffix-sum over equal-dst runs
    #pragma unroll
    for (int i = 0; i < 6; ++i) {
      const int off = 1 << i;
      #pragma unroll
      for (int j = 0; j < 4; ++j) {
        const float de = __shfl_down(ee[j], off, 64);
        const float dv = __shfl_down(vv[j], off, 64);
        if (take[i]) { ee[j] += de; vv[j] += dv; }
      }
    }
    if (head) {
      if (complete) {
        float4 r;
        r.x = fmaxf(vv[0] / (ee[0] + 1e-16f), 0.f);
        r.y = fmaxf(vv[1] / (ee[1] + 1e-16f), 0.f);
        r.z = fmaxf(vv[2] / (ee[2] + 1e-16f), 0.f);
        r.w = fmaxf(vv[3] / (ee[3] + 1e-16f), 0.f);
        *(float4*)(orow + c4 * 4) = r;
      } else {
        float4 a = {ee[0], ee[1], ee[2], ee[3]};
        float4 b = {vv[0], vv[1], vv[2], vv[3]};
        *(float4*)(srow + c4 * 8) = a;       // 32B sector {ee,vv}, written once
        *(float4*)(srow + c4 * 8 + 4) = b;
      }
    }
  }
}

// ---------------- finalize: empty rows -> 0; spanning dsts -> sum staging ----------------
__global__ __launch_bounds__(256) void finalize_kernel(const int* __restrict__ rowptr,
                                                       const float* __restrict__ stag,
                                                       float* __restrict__ out) {
  const int idx = blockIdx.x * 256 + threadIdx.x;  // NN*32 threads
  const int d = idx >> 5;
  const int c4 = idx & 31;
  if (d >= NN) return;
  const int r0 = rowptr[d];
  const int r1 = rowptr[d + 1];
  float4* o4 = (float4*)(out + (size_t)d * 128 + c4 * 4);
  if (r0 == r1) {                 // empty row
    const float4 z = {0.f, 0.f, 0.f, 0.f};
    *o4 = z;
    return;
  }
  const int w0 = r0 >> 6;
  const int w1 = (r1 - 1) >> 6;
  if (w0 == w1) return;           // complete-in-wave: written by edge_kernel
  float ee0 = 0.f, ee1 = 0.f, ee2 = 0.f, ee3 = 0.f;
  float vv0 = 0.f, vv1 = 0.f, vv2 = 0.f, vv3 = 0.f;
  int slot = 2 * w0 + 1;          // first partial; then 2w for w in (w0, w1]
  for (int w = w0; w <= w1; ++w) {
    const float* sp = stag + (size_t)slot * 256 + c4 * 8;
    const float4 a = *(const float4*)sp;
    const float4 b = *(const float4*)(sp + 4);
    ee0 += a.x; ee1 += a.y; ee2 += a.z; ee3 += a.w;
    vv0 += b.x; vv1 += b.y; vv2 += b.z; vv3 += b.w;
    slot = 2 * (w + 1);           // continuation slots
  }
  float4 r;
  r.x = fmaxf(vv0 / (ee0 + 1e-16f), 0.f);
  r.y = fmaxf(vv1 / (ee1 + 1e-16f), 0.f);
  r.z = fmaxf(vv2 / (ee2 + 1e-16f), 0.f);
  r.w = fmaxf(vv3 / (ee3 + 1e-16f), 0.f);
  *o4 = r;
}

extern "C" void kernel_launch(void* const* d_in, const int* in_sizes, int n_in,
                              void* d_out, int out_size, void* d_ws, size_t ws_size,
                              hipStream_t stream) {
  const float* x     = (const float*)d_in[0];
  const float* pos   = (const float*)d_in[1];
  const int*   ei    = (const int*)d_in[2];
  const float* W_lin = (const float*)d_in[3];
  const float* W_src = (const float*)d_in[4];
  const float* W_dst = (const float*)d_in[5];
  const float* Wp1   = (const float*)d_in[6];
  const float* bp1   = (const float*)d_in[7];
  const float* Wp2   = (const float*)d_in[8];
  const float* bp2   = (const float*)d_in[9];
  const float* Wa1   = (const float*)d_in[10];
  const float* ba1   = (const float*)d_in[11];
  const float* Wa2   = (const float*)d_in[12];
  const float* ba2   = (const float*)d_in[13];
  float* out = (float*)d_out;

  // workspace layout (~70 MB)
  float* h    = (float*)d_ws;                      // NN*128
  float* as1  = h   + (size_t)NN * 128;            // NN*64
  float* ad1  = as1 + (size_t)NN * 64;             // NN*64
  float* Wsa  = ad1 + (size_t)NN * 64;             // 128*64
  float* Wda  = Wsa + 128 * 64;                    // 128*64
  float* stag = Wda + 128 * 64;                    // 25000*256 floats
  int* counts   = (int*)(stag + (size_t)25000 * 256);  // NN
  int* ep       = counts + NN;                     // NN
  int* cursor   = ep + NN;                         // NN
  int* rowptr   = cursor + NN;                     // NN+1
  int* blocksum = rowptr + NN + 1;                 // 196
  int* blockoff = blocksum + 196;                  // 196
  int* ssrc     = blockoff + 196;                  // NE
  int* sdst     = ssrc + NE;                       // NE

  zero_counts<<<196, 256, 0, stream>>>(counts);
  count_kernel<<<3125, 256, 0, stream>>>(ei, counts);
  scan_block<<<196, 256, 0, stream>>>(counts, ep, blocksum);
  scan_tops<<<1, 64, 0, stream>>>(blocksum, blockoff, 196);
  scan_finish<<<196, 256, 0, stream>>>(ep, blockoff, cursor, rowptr);
  scatter_kernel<<<3125, 256, 0, stream>>>(ei, cursor, ssrc, sdst);
  fold_w<<<64, 256, 0, stream>>>(W_src, W_dst, Wa1, Wsa, Wda);
  gemm3_kernel<<<3125, 256, 0, stream>>>(x, W_lin, Wsa, Wda, h, as1, ad1);
  edge_kernel<<<6250, 128, 0, stream>>>(ssrc, sdst, rowptr, pos, h, as1, ad1,
                                        Wp1, bp1, Wp2, bp2, Wa1, ba1, Wa2, ba2,
                                        out, stag);
  finalize_kernel<<<6250, 256, 0, stream>>>(rowptr, stag, out);
}